// Round 7
// baseline (442.971 us; speedup 1.0000x reference)
//
#include <hip/hip_runtime.h>
#include <hip/hip_bf16.h>
#include <float.h>

#define Npts 16384
#define Dims 64
#define Oout 128
#define KNN  10
#define KC   16                      // coarse top-K per (segment, query) written out
#define LC   12                      // per-lane coarse list (tau source)
#define SEG  4
#define QT   64                      // queries per k_knn block
#define CT   128                     // candidates per chunk (hi-plane only)
#define QCAP 8                       // per-lane queue slots (invariant: <=7 used)
#define CAND_PER_SEG (Npts / SEG)    // 4096
#define CHUNKS (CAND_PER_SEG / CT)   // 32

typedef __attribute__((ext_vector_type(8))) short s16x8;
typedef __attribute__((ext_vector_type(4))) float f32x4;

__device__ __forceinline__ unsigned short f2bf(float f) {
    unsigned u = __float_as_uint(f);
    return (unsigned short)((u + 0x7FFFu + ((u >> 16) & 1u)) >> 16);
}

__device__ __forceinline__ void gl_lds16(const void* g, void* s) {
    __builtin_amdgcn_global_load_lds(
        (const __attribute__((address_space(1))) void*)g,
        (__attribute__((address_space(3))) void*)s,
        16, 0, 0);
}

__device__ __forceinline__ void insertL(float (&bd)[LC], int (&bi)[LC], float s, int j) {
    if (s < bd[LC - 1]) {
#pragma unroll
        for (int k = LC - 1; k >= 1; --k) {
            bool up = bd[k - 1] > s;
            float nd = up ? bd[k - 1] : ((bd[k] > s) ? s : bd[k]);
            int   ni = up ? bi[k - 1] : ((bd[k] > s) ? j : bi[k]);
            bd[k] = nd; bi[k] = ni;
        }
        bool u0 = bd[0] > s;
        bi[0] = u0 ? j : bi[0];
        bd[0] = u0 ? s : bd[0];
    }
}

// ------- k_tr: transpose + bf16 hi split + sq -------
__global__ __launch_bounds__(256) void k_tr(const float* __restrict__ x,
                                            float* __restrict__ ptsT,
                                            unsigned short* __restrict__ xh,
                                            float* __restrict__ sq) {
    __shared__ float tile[64][65];
    const int b = blockIdx.x;
    for (int i = threadIdx.x; i < 64 * 64; i += 256) {
        int d = i >> 6, p = i & 63;
        tile[d][p] = x[d * Npts + b * 64 + p];
    }
    __syncthreads();
    for (int i = threadIdx.x; i < 64 * 64; i += 256) {
        int p = i >> 6, d = i & 63;
        float v = tile[d][p];
        ptsT[(b * 64 + p) * 64 + d] = v;
        xh[(b * 64 + p) * 64 + d] = f2bf(v);
    }
    __syncthreads();
    if (threadIdx.x < 64) {
        int p = threadIdx.x;
        float a = 0.f;
#pragma unroll
        for (int d = 0; d < 64; ++d) { float v = tile[d][p]; a = fmaf(v, v, a); }
        sq[b * 64 + p] = a;
    }
}

// ------- k_y: y[n][o] = W[o]·pts[n] + b[o], LDS-tiled -------
__global__ __launch_bounds__(256) void k_y(const float* __restrict__ ptsT,
                                           const float* __restrict__ W,
                                           const float* __restrict__ bias,
                                           float* __restrict__ y) {
    __shared__ float wsh[128][65];
    __shared__ float xs[8][64];
    const int t = threadIdx.x;
    const int nb = blockIdx.x * 8;
    for (int i = t; i < 128 * 64; i += 256) {
        int o = i >> 6, d = i & 63;
        wsh[o][d] = W[i];
    }
    for (int i = t; i < 8 * 64; i += 256) {
        int n8 = i >> 6, d = i & 63;
        xs[n8][d] = ptsT[(nb + n8) * 64 + d];
    }
    __syncthreads();
    const int o = t & 127, nn = t >> 7;
    float a0 = bias[o], a1 = a0, a2 = a0, a3 = a0;
#pragma unroll
    for (int d = 0; d < 64; ++d) {
        float wv = wsh[o][d];
        a0 = fmaf(xs[nn * 4 + 0][d], wv, a0);
        a1 = fmaf(xs[nn * 4 + 1][d], wv, a1);
        a2 = fmaf(xs[nn * 4 + 2][d], wv, a2);
        a3 = fmaf(xs[nn * 4 + 3][d], wv, a3);
    }
    y[(nb + nn * 4 + 0) * 128 + o] = a0;
    y[(nb + nn * 4 + 1) * 128 + o] = a1;
    y[(nb + nn * 4 + 2) * 128 + o] = a2;
    y[(nb + nn * 4 + 3) * 128 + o] = a3;
}

// ------- k_knn: hi-only MFMA distances; insertL ONLY in wave-uniform branches -------
// grid: 256 qblocks x SEG. block 256 = 4 waves; wave w owns queries w*16..+15.
// S^T = mfma(A=cand, B=query): lane holds 4 scores for query (lane&15).
__global__ __launch_bounds__(256, 4) void k_knn(const unsigned short* __restrict__ xh,
                                                const float* __restrict__ sq,
                                                int* __restrict__ knnI) {
    __shared__ char smem[2][16384];        // staging dbuf: 128 cand x 128 B (hi)
    __shared__ float2 qq[4][64][QCAP];     // per-lane accept queues (16 KB)

    const int t    = threadIdx.x;
    const int w    = t >> 6;
    const int l    = t & 63;
    const int g    = l >> 4;           // k-group / D-row group
    const int q15  = l & 15;           // query column within wave
    const int qblk = blockIdx.x & 255;
    const int seg  = blockIdx.x >> 8;
    const int qbase = qblk * QT;
    const int swz  = (l & 7) << 4;     // A-read XOR swizzle (row&7 == q15&7)

    // B frags (queries), one-time global loads: k-slices g*8.. and 32+g*8..
    const int q = qbase + w * 16 + q15;
    const char* qhp = (const char*)xh + (size_t)q * 128;
    const s16x8 qh0 = *(const s16x8*)(qhp + g * 16);
    const s16x8 qh1 = *(const s16x8*)(qhp + 64 + g * 16);

    // staging source lane offset (pre-swizzled global -> linear LDS dest)
    const int loff = ((l >> 3) << 7) + (((l & 7) ^ (l >> 3)) << 4);

    float bd[LC]; int bi[LC];
#pragma unroll
    for (int k = 0; k < LC; ++k) { bd[k] = FLT_MAX; bi[k] = -1; }
    float tau = FLT_MAX;

    // prologue: stage chunk 0 (hi, 16 KB) into buf 0; wave w stages cands w*32..+31
    {
        const size_t sb = (size_t)(seg * CAND_PER_SEG + w * 32) * 128 + loff;
        const char* sH = (const char*)xh + sb;
        char* dH = smem[0] + w * 4096;
#pragma unroll
        for (int i = 0; i < 4; ++i) gl_lds16(sH + i * 1024, dH + i * 1024);
    }
    __syncthreads();

    for (int c = 0; c < CHUNKS; ++c) {
        if (c + 1 < CHUNKS) {
            const size_t sb = (size_t)(seg * CAND_PER_SEG + (c + 1) * CT + w * 32) * 128 + loff;
            const char* sH = (const char*)xh + sb;
            char* dH = smem[(c + 1) & 1] + w * 4096;
#pragma unroll
            for (int i = 0; i < 4; ++i) gl_lds16(sH + i * 1024, dH + i * 1024);
        }

        const char* hb = smem[c & 1];
        const int jb = seg * CAND_PER_SEG + c * CT;

        if (c == 0) {
            // seed pass (wave-uniform path): direct insert, tau set once at end
#pragma unroll
            for (int ct = 0; ct < 8; ++ct) {
                const int ro = (ct * 16 + q15) * 128;
                const s16x8 ah0 = *(const s16x8*)(hb + ro + ((g * 16) ^ swz));
                const s16x8 ah1 = *(const s16x8*)(hb + ro + ((64 + g * 16) ^ swz));
                f32x4 acc = {0.f, 0.f, 0.f, 0.f};
                acc = __builtin_amdgcn_mfma_f32_16x16x32_bf16(ah0, qh0, acc, 0, 0, 0);
                acc = __builtin_amdgcn_mfma_f32_16x16x32_bf16(ah1, qh1, acc, 0, 0, 0);
                const int j0 = jb + ct * 16 + g * 4;
                const float4 s4 = *(const float4*)(sq + j0);
                insertL(bd, bi, fmaf(-2.f, acc[0], s4.x), j0 + 0);
                insertL(bd, bi, fmaf(-2.f, acc[1], s4.y), j0 + 1);
                insertL(bd, bi, fmaf(-2.f, acc[2], s4.z), j0 + 2);
                insertL(bd, bi, fmaf(-2.f, acc[3], s4.w), j0 + 3);
            }
            float t15 = bd[LC - 1];
            t15 = fminf(t15, __shfl_xor(t15, 16, 64));
            t15 = fminf(t15, __shfl_xor(t15, 32, 64));
            tau = t15;
        } else {
            int myq = 0;                 // per-lane queue count (register)
#pragma unroll
            for (int ct = 0; ct < 8; ++ct) {
                const int ro = (ct * 16 + q15) * 128;
                const s16x8 ah0 = *(const s16x8*)(hb + ro + ((g * 16) ^ swz));
                const s16x8 ah1 = *(const s16x8*)(hb + ro + ((64 + g * 16) ^ swz));
                f32x4 acc = {0.f, 0.f, 0.f, 0.f};
                acc = __builtin_amdgcn_mfma_f32_16x16x32_bf16(ah0, qh0, acc, 0, 0, 0);
                acc = __builtin_amdgcn_mfma_f32_16x16x32_bf16(ah1, qh1, acc, 0, 0, 0);
                const int j0 = jb + ct * 16 + g * 4;
                const float4 s4 = *(const float4*)(sq + j0);
                const float ss[4] = {fmaf(-2.f, acc[0], s4.x), fmaf(-2.f, acc[1], s4.y),
                                     fmaf(-2.f, acc[2], s4.z), fmaf(-2.f, acc[3], s4.w)};
                // divergent path: queue-write ONLY (~5 inst), no insert anywhere
#pragma unroll
                for (int u = 0; u < 4; ++u) {
                    if (ss[u] < tau)
                        qq[w][l][myq++] = make_float2(ss[u], __int_as_float(j0 + u));
                }
                // wave-uniform overflow-prevention drain (scalar branch, rare)
                if (__any(myq >= QCAP - 4)) {
                    for (int i = 0; i < myq; ++i) {
                        float2 e = qq[w][l][i];
                        insertL(bd, bi, e.x, __float_as_int(e.y));
                    }
                    myq = 0;
                    float t15 = bd[LC - 1];
                    t15 = fminf(t15, __shfl_xor(t15, 16, 64));
                    t15 = fminf(t15, __shfl_xor(t15, 32, 64));
                    tau = t15;
                }
            }
            // wave-uniform end-of-chunk drain (skipped when wave accepted nothing)
            if (__any(myq != 0)) {
                for (int i = 0; i < myq; ++i) {
                    float2 e = qq[w][l][i];
                    insertL(bd, bi, e.x, __float_as_int(e.y));
                }
                float t15 = bd[LC - 1];
                t15 = fminf(t15, __shfl_xor(t15, 16, 64));
                t15 = fminf(t15, __shfl_xor(t15, 32, 64));
                tau = t15;
            }
        }
        __syncthreads();   // staging drain + buffer swap
    }

    // merge 4 per-lane sorted lists (LC each) per query -> segment top-16
    float* mD = (float*)smem[0];         // 64q x 4g x LC = 3072 floats
    int*   mI = (int*)smem[1];
    const int qb = w * 16 + q15;
#pragma unroll
    for (int k = 0; k < LC; ++k) {
        mD[(qb * 4 + g) * LC + k] = bd[k];
        mI[(qb * 4 + g) * LC + k] = bi[k];
    }
    __syncthreads();

    if (t < QT) {
        const int base = t * 4 * LC;
        int p0 = 0, p1 = 0, p2 = 0, p3 = 0;
        int* outp = knnI + (size_t)(seg * Npts + qbase + t) * KC;
        for (int k = 0; k < KC; ++k) {
            float v0 = (p0 < LC) ? mD[base + p0]          : FLT_MAX;
            float v1 = (p1 < LC) ? mD[base + LC + p1]     : FLT_MAX;
            float v2 = (p2 < LC) ? mD[base + 2 * LC + p2] : FLT_MAX;
            float v3 = (p3 < LC) ? mD[base + 3 * LC + p3] : FLT_MAX;
            float bv = v0; int bs = 0;
            if (v1 < bv) { bv = v1; bs = 1; }
            if (v2 < bv) { bv = v2; bs = 2; }
            if (v3 < bv) { bv = v3; bs = 3; }
            int off = (bs == 0) ? p0 : (bs == 1) ? p1 : (bs == 2) ? p2 : p3;
            outp[k] = mI[base + bs * LC + off];
            if (bs == 0) ++p0; else if (bs == 1) ++p1; else if (bs == 2) ++p2; else ++p3;
        }
    }
}

// ------- k_out: fp64 exact re-rank of 64 coarse candidates -> top-10 -> gather-max -------
__global__ __launch_bounds__(128) void k_out(const float* __restrict__ y,
                                             const float* __restrict__ ptsT,
                                             const int* __restrict__ knnI,
                                             float* __restrict__ out) {
    __shared__ float  qs[Dims];
    __shared__ int    cidx[SEG * KC];
    __shared__ double d2s[SEG * KC];
    __shared__ int    nb[KNN];
    const int n = blockIdx.x;
    const int t = threadIdx.x;

    if (t < Dims) qs[t] = ptsT[n * Dims + t];
    if (t < SEG * KC)
        cidx[t] = knnI[(size_t)((t >> 4) * Npts + n) * KC + (t & 15)];
    __syncthreads();

    if (t < SEG * KC) {
        const int j = cidx[t];
        double acc = 0.0;
#pragma unroll
        for (int d4 = 0; d4 < Dims / 4; ++d4) {
            const float4 pv = *reinterpret_cast<const float4*>(&ptsT[j * Dims + d4 * 4]);
            const float4 qv = *reinterpret_cast<const float4*>(&qs[d4 * 4]);
            double e0 = (double)qv.x - (double)pv.x;
            double e1 = (double)qv.y - (double)pv.y;
            double e2 = (double)qv.z - (double)pv.z;
            double e3 = (double)qv.w - (double)pv.w;
            acc = fma(e0, e0, acc); acc = fma(e1, e1, acc);
            acc = fma(e2, e2, acc); acc = fma(e3, e3, acc);
        }
        d2s[t] = acc;
    }
    __syncthreads();

    if (t < SEG * KC) {
        const double dv = d2s[t]; const int ji = cidx[t];
        int rank = 0;
        for (int c = 0; c < SEG * KC; ++c) {
            bool less = (d2s[c] < dv) || (d2s[c] == dv && cidx[c] < ji);
            rank += less ? 1 : 0;
        }
        if (rank < KNN) nb[rank] = ji;
    }
    __syncthreads();

    float m = -FLT_MAX;
#pragma unroll
    for (int k = 0; k < KNN; ++k)
        m = fmaxf(m, y[(size_t)nb[k] * Oout + t]);
    out[(size_t)n * Oout + t] = m;
}

// ---------------- launcher ----------------
extern "C" void kernel_launch(void* const* d_in, const int* in_sizes, int n_in,
                              void* d_out, int out_size, void* d_ws, size_t ws_size,
                              hipStream_t stream) {
    const float* x = (const float*)d_in[0];   // (1, 64, 16384)
    const float* W = (const float*)d_in[1];   // (128, 64)
    const float* b = (const float*)d_in[2];   // (128,)
    float* out = (float*)d_out;

    float* ws   = (float*)d_ws;
    float* sq   = ws;                                   // 16384
    float* ptsT = ws + Npts;                            // N*D  (4 MB)
    float* y    = ptsT + Npts * Dims;                   // N*O  (8 MB)
    unsigned short* xh = (unsigned short*)(y + Npts * Oout);  // N*D bf16 (2 MB)
    int* knnI   = (int*)(xh + Npts * Dims);             // SEG*N*KC (4 MB)

    k_tr <<<Npts / 64, 256, 0, stream>>>(x, ptsT, xh, sq);
    k_y  <<<Npts / 8, 256, 0, stream>>>(ptsT, W, b, y);
    k_knn<<<(Npts / QT) * SEG, 256, 0, stream>>>(xh, sq, knnI);
    k_out<<<Npts, 128, 0, stream>>>(y, ptsT, knnI, out);
}

// Round 8
// 371.939 us; speedup vs baseline: 1.1910x; 1.1910x over previous
//
#include <hip/hip_runtime.h>
#include <hip/hip_bf16.h>
#include <float.h>

#define Npts 16384
#define Dims 64
#define Oout 128
#define KNN  10
#define LC   12                      // per-stream top-K list
#define NR   16                      // candidate ranges
#define RLEN (Npts / NR)             // 1024 candidates per range
#define CT   64                      // candidates per chunk
#define NCH  (RLEN / CT)             // 16 chunks
#define QCAP 20                      // queue slots (+1 pad)

typedef __attribute__((ext_vector_type(8))) short s16x8;
typedef __attribute__((ext_vector_type(4))) float f32x4;

__device__ __forceinline__ unsigned short f2bf(float f) {
    unsigned u = __float_as_uint(f);
    return (unsigned short)((u + 0x7FFFu + ((u >> 16) & 1u)) >> 16);
}

__device__ __forceinline__ void insertL(float (&bd)[LC], int (&bi)[LC], float s, int j) {
    if (s < bd[LC - 1]) {
#pragma unroll
        for (int k = LC - 1; k >= 1; --k) {
            bool up = bd[k - 1] > s;
            float nd = up ? bd[k - 1] : ((bd[k] > s) ? s : bd[k]);
            int   ni = up ? bi[k - 1] : ((bd[k] > s) ? j : bi[k]);
            bd[k] = nd; bi[k] = ni;
        }
        bool u0 = bd[0] > s;
        bi[0] = u0 ? j : bi[0];
        bd[0] = u0 ? s : bd[0];
    }
}

// ------- k_tr: transpose + bf16 hi split + sq -------
__global__ __launch_bounds__(256) void k_tr(const float* __restrict__ x,
                                            float* __restrict__ ptsT,
                                            unsigned short* __restrict__ xh,
                                            float* __restrict__ sq) {
    __shared__ float tile[64][65];
    const int b = blockIdx.x;
    for (int i = threadIdx.x; i < 64 * 64; i += 256) {
        int d = i >> 6, p = i & 63;
        tile[d][p] = x[d * Npts + b * 64 + p];
    }
    __syncthreads();
    for (int i = threadIdx.x; i < 64 * 64; i += 256) {
        int p = i >> 6, d = i & 63;
        float v = tile[d][p];
        ptsT[(b * 64 + p) * 64 + d] = v;
        xh[(b * 64 + p) * 64 + d] = f2bf(v);
    }
    __syncthreads();
    if (threadIdx.x < 64) {
        int p = threadIdx.x;
        float a = 0.f;
#pragma unroll
        for (int d = 0; d < 64; ++d) { float v = tile[d][p]; a = fmaf(v, v, a); }
        sq[b * 64 + p] = a;
    }
}

// ------- k_y: y[n][o] = W[o]·pts[n] + b[o], LDS-tiled -------
__global__ __launch_bounds__(256) void k_y(const float* __restrict__ ptsT,
                                           const float* __restrict__ W,
                                           const float* __restrict__ bias,
                                           float* __restrict__ y) {
    __shared__ float wsh[128][65];
    __shared__ float xs[8][64];
    const int t = threadIdx.x;
    const int nb = blockIdx.x * 8;
    for (int i = t; i < 128 * 64; i += 256) {
        int o = i >> 6, d = i & 63;
        wsh[o][d] = W[i];
    }
    for (int i = t; i < 8 * 64; i += 256) {
        int n8 = i >> 6, d = i & 63;
        xs[n8][d] = ptsT[(nb + n8) * 64 + d];
    }
    __syncthreads();
    const int o = t & 127, nn = t >> 7;
    float a0 = bias[o], a1 = a0, a2 = a0, a3 = a0;
#pragma unroll
    for (int d = 0; d < 64; ++d) {
        float wv = wsh[o][d];
        a0 = fmaf(xs[nn * 4 + 0][d], wv, a0);
        a1 = fmaf(xs[nn * 4 + 1][d], wv, a1);
        a2 = fmaf(xs[nn * 4 + 2][d], wv, a2);
        a3 = fmaf(xs[nn * 4 + 3][d], wv, a3);
    }
    y[(nb + nn * 4 + 0) * 128 + o] = a0;
    y[(nb + nn * 4 + 1) * 128 + o] = a1;
    y[(nb + nn * 4 + 2) * 128 + o] = a2;
    y[(nb + nn * 4 + 3) * 128 + o] = a3;
}

// ------- k_knn: one lane = one query; wave-private, barrier-free -------
// grid: 256 qblocks x 4 rangeblocks; block 256 = 4 waves.
// Wave w handles range rb*4+w (1024 cands) for the block's 64 queries.
__global__ __launch_bounds__(256, 3) void k_knn(const unsigned short* __restrict__ xh,
                                                const float* __restrict__ sq,
                                                float* __restrict__ outS,
                                                unsigned short* __restrict__ outI) {
    __shared__ __align__(16) float tile[4][4][16][20];  // [wave][qg][col][16+4pad]
    __shared__ unsigned qq[4][64][QCAP + 1];            // per-lane queue (+pad slot)

    const int t    = threadIdx.x;
    const int w    = t >> 6;
    const int l    = t & 63;
    const int c15  = l & 15;
    const int g    = l >> 4;
    const int qblk = blockIdx.x & 255;
    const int rb   = blockIdx.x >> 8;
    const int range = rb * 4 + w;
    const int q     = qblk * 64 + l;       // lane's own query
    const int cb0   = range * RLEN;

    // B-frags: 4 query-groups x 2 k-slices (col=c15, k-slice g*8 / 32+g*8)
    s16x8 b0[4], b1[4];
#pragma unroll
    for (int qg = 0; qg < 4; ++qg) {
        const unsigned short* qp = xh + (size_t)(qblk * 64 + qg * 16 + c15) * 64 + g * 8;
        b0[qg] = *(const s16x8*)qp;
        b1[qg] = *(const s16x8*)(qp + 32);
    }

    float bd[LC]; int bi[LC];
#pragma unroll
    for (int k = 0; k < LC; ++k) { bd[k] = FLT_MAX; bi[k] = -1; }
    float tau = FLT_MAX;
    int myq = 0;
    unsigned* myqq = &qq[w][l][0];

    for (int ch = 0; ch < NCH; ++ch) {
        const int cb = cb0 + ch * CT;

        // A-frags for the whole chunk (4 cand-groups x 2 k-slices), direct global
        s16x8 A0[4], A1[4];
#pragma unroll
        for (int cg = 0; cg < 4; ++cg) {
            const unsigned short* ap = xh + (size_t)(cb + cg * 16 + c15) * 64 + g * 8;
            A0[cg] = *(const s16x8*)ap;
            A1[cg] = *(const s16x8*)(ap + 32);
        }

#pragma unroll
        for (int cg = 0; cg < 4; ++cg) {
            // scores for 64 queries x 16 cands: 4 qg-tiles, bounced via LDS
#pragma unroll
            for (int qg = 0; qg < 4; ++qg) {
                f32x4 acc = {0.f, 0.f, 0.f, 0.f};
                acc = __builtin_amdgcn_mfma_f32_16x16x32_bf16(A0[cg], b0[qg], acc, 0, 0, 0);
                acc = __builtin_amdgcn_mfma_f32_16x16x32_bf16(A1[cg], b1[qg], acc, 0, 0, 0);
                *(f32x4*)&tile[w][qg][c15][g * 4] = acc;   // col=query(c15), rows=cands
            }
            __builtin_amdgcn_wave_barrier();
            asm volatile("s_waitcnt lgkmcnt(0)" ::: "memory");
            __builtin_amdgcn_sched_barrier(0);

            // lane reads its own query's 16 scores (qg = l>>4 -> base = l*80B)
            const f32x4 r0 = *(const f32x4*)&tile[w][g][c15][0];
            const f32x4 r1 = *(const f32x4*)&tile[w][g][c15][4];
            const f32x4 r2 = *(const f32x4*)&tile[w][g][c15][8];
            const f32x4 r3 = *(const f32x4*)&tile[w][g][c15][12];
            __builtin_amdgcn_wave_barrier();

            const float* sp = sq + cb + cg * 16;   // wave-uniform -> s_loads
            float sv[16];
#pragma unroll
            for (int i = 0; i < 4; ++i) {
                sv[i]      = fmaf(-2.f, r0[i], sp[i]);
                sv[4 + i]  = fmaf(-2.f, r1[i], sp[4 + i]);
                sv[8 + i]  = fmaf(-2.f, r2[i], sp[8 + i]);
                sv[12 + i] = fmaf(-2.f, r3[i], sp[12 + i]);
            }
            // branchless enqueue: unconditional write, conditional bump
#pragma unroll
            for (int i = 0; i < 16; ++i) {
                unsigned e = (__float_as_uint(sv[i]) & ~63u) | (unsigned)(cg * 16 + i);
                myqq[myq] = e;
                myq += (sv[i] < tau) ? 1 : 0;
            }
            // wave-uniform guard: keep headroom for next cg (<=16 accepts)
            if (__any(myq > QCAP - 16)) {
                for (int i = 0; i < myq; ++i) {
                    unsigned e = myqq[i];
                    insertL(bd, bi, __uint_as_float(e & ~63u), cb + (int)(e & 63u));
                }
                myq = 0;
                tau = bd[LC - 1];
            }
        }
        // end-of-chunk drain (loc bits are chunk-relative)
        if (__any(myq != 0)) {
            for (int i = 0; i < myq; ++i) {
                unsigned e = myqq[i];
                insertL(bd, bi, __uint_as_float(e & ~63u), cb + (int)(e & 63u));
            }
            myq = 0;
            tau = bd[LC - 1];
        }
    }

    // write this (range, query) sorted top-12
    float* os = outS + ((size_t)range * Npts + q) * LC;
    unsigned short* oi = outI + ((size_t)range * Npts + q) * LC;
#pragma unroll
    for (int k = 0; k < LC; ++k) {
        os[k] = bd[k];
        oi[k] = (unsigned short)bi[k];
    }
}

// ------- k_out: 192 coarse -> top24 (2-phase rank) -> fp64 top10 -> gather-max -------
__global__ __launch_bounds__(192) void k_out(const float* __restrict__ y,
                                             const float* __restrict__ ptsT,
                                             const float* __restrict__ outS,
                                             const unsigned short* __restrict__ outI,
                                             float* __restrict__ out) {
    __shared__ float  sc[NR * LC];
    __shared__ int    ix[NR * LC];
    __shared__ float  s2[96];
    __shared__ int    i2[96];
    __shared__ int    c24[24];
    __shared__ double d2s[24];
    __shared__ int    ci[24];
    __shared__ __align__(16) float qs[Dims];
    __shared__ int    nb[KNN];

    const int n = blockIdx.x;
    const int t = threadIdx.x;

    if (t < Dims) qs[t] = ptsT[(size_t)n * Dims + t];
    {
        const int r = t / LC, k = t - r * LC;   // t < 192 = NR*LC
        sc[t] = outS[((size_t)r * Npts + n) * LC + k];
        ix[t] = (int)outI[((size_t)r * Npts + n) * LC + k];
    }
    __syncthreads();

    // phase 1: rank within group of 48, keep top-24 of each (4 groups -> 96)
    {
        const int gb = (t / 48) * 48;
        const float v = sc[t]; const int vi = ix[t];
        int rk = 0;
        for (int c = 0; c < 48; ++c) {
            float oc = sc[gb + c]; int oi = ix[gb + c];
            rk += (oc < v || (oc == v && oi < vi)) ? 1 : 0;
        }
        if (rk < 24) { s2[(t / 48) * 24 + rk] = v; i2[(t / 48) * 24 + rk] = vi; }
    }
    __syncthreads();

    // phase 2: 96 -> coarse top-24
    if (t < 96) {
        const float v = s2[t]; const int vi = i2[t];
        int rk = 0;
        for (int c = 0; c < 96; ++c)
            rk += (s2[c] < v || (s2[c] == v && i2[c] < vi)) ? 1 : 0;
        if (rk < 24) c24[rk] = vi;
    }
    __syncthreads();

    // exact fp64 d2 for 24 candidates
    if (t < 24) {
        const int j = c24[t];
        double acc = 0.0;
#pragma unroll
        for (int d4 = 0; d4 < Dims / 4; ++d4) {
            const float4 pv = *(const float4*)&ptsT[(size_t)j * Dims + d4 * 4];
            const float4 qv = *(const float4*)&qs[d4 * 4];
            double e0 = (double)qv.x - (double)pv.x;
            double e1 = (double)qv.y - (double)pv.y;
            double e2 = (double)qv.z - (double)pv.z;
            double e3 = (double)qv.w - (double)pv.w;
            acc = fma(e0, e0, acc); acc = fma(e1, e1, acc);
            acc = fma(e2, e2, acc); acc = fma(e3, e3, acc);
        }
        d2s[t] = acc; ci[t] = j;
    }
    __syncthreads();

    // exact top-10 by (d2, idx)
    if (t < 24) {
        const double dv = d2s[t]; const int ji = ci[t];
        int rk = 0;
        for (int c = 0; c < 24; ++c)
            rk += (d2s[c] < dv || (d2s[c] == dv && ci[c] < ji)) ? 1 : 0;
        if (rk < KNN) nb[rk] = ji;
    }
    __syncthreads();

    if (t < Oout) {
        float m = -FLT_MAX;
#pragma unroll
        for (int k = 0; k < KNN; ++k)
            m = fmaxf(m, y[(size_t)nb[k] * Oout + t]);
        out[(size_t)n * Oout + t] = m;
    }
}

// ---------------- launcher ----------------
extern "C" void kernel_launch(void* const* d_in, const int* in_sizes, int n_in,
                              void* d_out, int out_size, void* d_ws, size_t ws_size,
                              hipStream_t stream) {
    const float* x = (const float*)d_in[0];   // (1, 64, 16384)
    const float* W = (const float*)d_in[1];   // (128, 64)
    const float* b = (const float*)d_in[2];   // (128,)
    float* out = (float*)d_out;

    float* ws   = (float*)d_ws;
    float* sq   = ws;                                        // 16384        (64 KB)
    float* ptsT = ws + Npts;                                 // N*D          (4 MB)
    float* y    = ptsT + Npts * Dims;                        // N*O          (8 MB)
    unsigned short* xh = (unsigned short*)(y + Npts * Oout); // N*D bf16     (2 MB)
    float* outS = (float*)(xh + Npts * Dims);                // NR*N*LC f32  (12 MB)
    unsigned short* outI = (unsigned short*)(outS + (size_t)NR * Npts * LC); // (6 MB)

    k_tr <<<Npts / 64, 256, 0, stream>>>(x, ptsT, xh, sq);
    k_y  <<<Npts / 8, 256, 0, stream>>>(ptsT, W, b, y);
    k_knn<<<256 * 4, 256, 0, stream>>>(xh, sq, outS, outI);
    k_out<<<Npts, 192, 0, stream>>>(y, ptsT, outS, outI, out);
}

// Round 9
// 358.819 us; speedup vs baseline: 1.2345x; 1.0366x over previous
//
#include <hip/hip_runtime.h>
#include <hip/hip_bf16.h>
#include <float.h>

#define Npts 16384
#define Dims 64
#define Oout 128
#define KNN  10
#define LC   12                      // per-query coarse list
#define NR   16                      // candidate ranges
#define RLEN (Npts / NR)             // 1024
#define NCG  (RLEN / 16)             // 64 cand-groups of 16
#define QCAP 20                      // queue slots

typedef __attribute__((ext_vector_type(8))) short s16x8;
typedef __attribute__((ext_vector_type(4))) float f32x4;

__device__ __forceinline__ unsigned short f2bf(float f) {
    unsigned u = __float_as_uint(f);
    return (unsigned short)((u + 0x7FFFu + ((u >> 16) & 1u)) >> 16);
}
__device__ __forceinline__ float bf2f(unsigned short b) {
    return __uint_as_float(((unsigned)b) << 16);
}
// bf16 * (-2): flip sign, exp+1 (exact; zero/denorm handled)
__device__ __forceinline__ short neg2(short hs) {
    unsigned short h = (unsigned short)hs;
    unsigned short m = (unsigned short)(h ^ 0x8000u);
    return (short)(((h & 0x7F80u) == 0) ? m : (unsigned short)(m + 0x0080u));
}

__device__ __forceinline__ void insertL(float (&bd)[LC], int (&bi)[LC], float s, int j) {
    if (s < bd[LC - 1]) {
#pragma unroll
        for (int k = LC - 1; k >= 1; --k) {
            bool up = bd[k - 1] > s;
            float nd = up ? bd[k - 1] : ((bd[k] > s) ? s : bd[k]);
            int   ni = up ? bi[k - 1] : ((bd[k] > s) ? j : bi[k]);
            bd[k] = nd; bi[k] = ni;
        }
        bool u0 = bd[0] > s;
        bi[0] = u0 ? j : bi[0];
        bd[0] = u0 ? s : bd[0];
    }
}

// ------- k_tr: transpose + bf16 hi split + sq -------
__global__ __launch_bounds__(256) void k_tr(const float* __restrict__ x,
                                            float* __restrict__ ptsT,
                                            unsigned short* __restrict__ xh,
                                            float* __restrict__ sq) {
    __shared__ float tile[64][65];
    const int b = blockIdx.x;
    for (int i = threadIdx.x; i < 64 * 64; i += 256) {
        int d = i >> 6, p = i & 63;
        tile[d][p] = x[d * Npts + b * 64 + p];
    }
    __syncthreads();
    for (int i = threadIdx.x; i < 64 * 64; i += 256) {
        int p = i >> 6, d = i & 63;
        float v = tile[d][p];
        ptsT[(b * 64 + p) * 64 + d] = v;
        xh[(b * 64 + p) * 64 + d] = (unsigned short)f2bf(v);
    }
    __syncthreads();
    if (threadIdx.x < 64) {
        int p = threadIdx.x;
        float a = 0.f;
#pragma unroll
        for (int d = 0; d < 64; ++d) { float v = tile[d][p]; a = fmaf(v, v, a); }
        sq[b * 64 + p] = a;
    }
}

// ------- k_y: y[n][o] = W[o]·pts[n] + b[o], LDS-tiled -------
__global__ __launch_bounds__(256) void k_y(const float* __restrict__ ptsT,
                                           const float* __restrict__ W,
                                           const float* __restrict__ bias,
                                           float* __restrict__ y) {
    __shared__ float wsh[128][65];
    __shared__ float xs[8][64];
    const int t = threadIdx.x;
    const int nb = blockIdx.x * 8;
    for (int i = t; i < 128 * 64; i += 256) {
        int o = i >> 6, d = i & 63;
        wsh[o][d] = W[i];
    }
    for (int i = t; i < 8 * 64; i += 256) {
        int n8 = i >> 6, d = i & 63;
        xs[n8][d] = ptsT[(nb + n8) * 64 + d];
    }
    __syncthreads();
    const int o = t & 127, nn = t >> 7;
    float a0 = bias[o], a1 = a0, a2 = a0, a3 = a0;
#pragma unroll
    for (int d = 0; d < 64; ++d) {
        float wv = wsh[o][d];
        a0 = fmaf(xs[nn * 4 + 0][d], wv, a0);
        a1 = fmaf(xs[nn * 4 + 1][d], wv, a1);
        a2 = fmaf(xs[nn * 4 + 2][d], wv, a2);
        a3 = fmaf(xs[nn * 4 + 3][d], wv, a3);
    }
    y[(nb + nn * 4 + 0) * 128 + o] = a0;
    y[(nb + nn * 4 + 1) * 128 + o] = a1;
    y[(nb + nn * 4 + 2) * 128 + o] = a2;
    y[(nb + nn * 4 + 3) * 128 + o] = a3;
}

// ------- k_knn: pipelined MFMA + LDS bounce, no fences, scalar sq -------
// grid: 256 qblocks x 4 rangeblocks; block 256 = 4 waves.
// Wave w handles range rb*4+w (1024 cands) for the block's 64 queries.
__global__ __launch_bounds__(256, 4) void k_knn(const unsigned short* __restrict__ xh,
                                                const float* __restrict__ sq,
                                                float* __restrict__ outS,
                                                unsigned short* __restrict__ outI) {
    __shared__ __align__(16) float tile[4][4][16][20];  // [wave][qg][col][16+4pad]
    __shared__ unsigned qq[4][64][QCAP + 1];            // per-lane queues

    const int t    = threadIdx.x;
    const int w    = __builtin_amdgcn_readfirstlane(t >> 6);   // uniform wave id
    const int l    = t & 63;
    const int c15  = l & 15;
    const int g    = l >> 4;
    const int qblk = blockIdx.x & 255;
    const int rb   = blockIdx.x >> 8;
    const int range = rb * 4 + w;
    const int rbase = range * RLEN;
    const float* sqp = sq + rbase;                       // uniform -> s_loads
    const unsigned short* xr = xh + (size_t)rbase * 64;

    // B-frags: queries scaled by -2 in bf16 (exact), so MFMA acc = -2*q.c
    s16x8 b0[4], b1[4];
#pragma unroll
    for (int qg = 0; qg < 4; ++qg) {
        const unsigned short* qp = xh + (size_t)(qblk * 64 + qg * 16 + c15) * 64 + g * 8;
        s16x8 h0 = *(const s16x8*)qp;
        s16x8 h1 = *(const s16x8*)(qp + 32);
#pragma unroll
        for (int e = 0; e < 8; ++e) { b0[qg][e] = neg2(h0[e]); b1[qg][e] = neg2(h1[e]); }
    }

    float bd[LC]; int bi[LC];
#pragma unroll
    for (int k = 0; k < LC; ++k) { bd[k] = FLT_MAX; bi[k] = -1; }
    float tau = FLT_MAX;
    int myq = 0;
    unsigned* myqq = &qq[w][l][0];

    // pipeline state: pending scores (prev group) + its sq slice + base idx
    f32x4 p0 = {FLT_MAX, FLT_MAX, FLT_MAX, FLT_MAX}, p1 = p0, p2 = p0, p3 = p0;
    float sp[16];
#pragma unroll
    for (int j = 0; j < 16; ++j) sp[j] = 0.f;
    int pb = 0;

    // A-frag prefetch (group 0)
    const unsigned short* ap0 = xr + (size_t)c15 * 64 + g * 8;
    s16x8 Ac0 = *(const s16x8*)ap0;
    s16x8 Ac1 = *(const s16x8*)(ap0 + 32);

    for (int ci = 0; ci < NCG; ++ci) {
        // prefetch next group's A-frags
        const int cn = (ci + 1 < NCG) ? ci + 1 : ci;
        const unsigned short* apn = xr + (size_t)(cn * 16 + c15) * 64 + g * 8;
        s16x8 An0 = *(const s16x8*)apn;
        s16x8 An1 = *(const s16x8*)(apn + 32);

        // sq slice for THIS group (consumed next iteration) - scalar loads
        float sn[16];
#pragma unroll
        for (int j = 0; j < 16; ++j) sn[j] = sqp[ci * 16 + j];

        // MFMA + LDS bounce (no fence: same-wave DS is in-order)
#pragma unroll
        for (int qg = 0; qg < 4; ++qg) {
            f32x4 acc = {0.f, 0.f, 0.f, 0.f};
            acc = __builtin_amdgcn_mfma_f32_16x16x32_bf16(Ac0, b0[qg], acc, 0, 0, 0);
            acc = __builtin_amdgcn_mfma_f32_16x16x32_bf16(Ac1, b1[qg], acc, 0, 0, 0);
            *(f32x4*)&tile[w][qg][c15][g * 4] = acc;
        }
        f32x4 n0 = *(const f32x4*)&tile[w][g][c15][0];
        f32x4 n1 = *(const f32x4*)&tile[w][g][c15][4];
        f32x4 n2 = *(const f32x4*)&tile[w][g][c15][8];
        f32x4 n3 = *(const f32x4*)&tile[w][g][c15][12];

        // filter PREVIOUS group's scores (regs long since waited)
        {
            const float sv[16] = {
                p0[0] + sp[0],  p0[1] + sp[1],  p0[2] + sp[2],  p0[3] + sp[3],
                p1[0] + sp[4],  p1[1] + sp[5],  p1[2] + sp[6],  p1[3] + sp[7],
                p2[0] + sp[8],  p2[1] + sp[9],  p2[2] + sp[10], p2[3] + sp[11],
                p3[0] + sp[12], p3[1] + sp[13], p3[2] + sp[14], p3[3] + sp[15]};
#pragma unroll
            for (int j = 0; j < 16; ++j) {
                unsigned e = (__float_as_uint(sv[j]) & ~1023u) | (unsigned)(pb + j);
                myqq[myq] = e;                      // unconditional write
                myq += (sv[j] < tau) ? 1 : 0;      // conditional bump
            }
        }

        // wave-uniform drain guard (keeps headroom invariant: myq<=4 at filter entry)
        if (__any(myq > QCAP - 16)) {
            for (int i = 0; i < myq; ++i) {
                unsigned e = myqq[i];
                insertL(bd, bi, __uint_as_float(e & ~1023u), rbase + (int)(e & 1023u));
            }
            myq = 0;
            tau = bd[LC - 1];
        }

        // rotate pipeline state (waits for this group's ds_reads land here)
        p0 = n0; p1 = n1; p2 = n2; p3 = n3;
#pragma unroll
        for (int j = 0; j < 16; ++j) sp[j] = sn[j];
        pb = ci * 16;
        Ac0 = An0; Ac1 = An1;
    }

    // final pending group
    {
        const float sv[16] = {
            p0[0] + sp[0],  p0[1] + sp[1],  p0[2] + sp[2],  p0[3] + sp[3],
            p1[0] + sp[4],  p1[1] + sp[5],  p1[2] + sp[6],  p1[3] + sp[7],
            p2[0] + sp[8],  p2[1] + sp[9],  p2[2] + sp[10], p2[3] + sp[11],
            p3[0] + sp[12], p3[1] + sp[13], p3[2] + sp[14], p3[3] + sp[15]};
#pragma unroll
        for (int j = 0; j < 16; ++j) {
            unsigned e = (__float_as_uint(sv[j]) & ~1023u) | (unsigned)(pb + j);
            myqq[myq] = e;
            myq += (sv[j] < tau) ? 1 : 0;
        }
    }
    if (__any(myq != 0)) {
        for (int i = 0; i < myq; ++i) {
            unsigned e = myqq[i];
            insertL(bd, bi, __uint_as_float(e & ~1023u), rbase + (int)(e & 1023u));
        }
    }

    // write this (range, query) sorted top-12
    const int q = qblk * 64 + l;
    float* os = outS + ((size_t)range * Npts + q) * LC;
    unsigned short* oi = outI + ((size_t)range * Npts + q) * LC;
#pragma unroll
    for (int k = 0; k < LC; ++k) {
        os[k] = bd[k];
        oi[k] = (unsigned short)bi[k];
    }
}

// ------- k_out: 192 coarse -> top24 (2-phase rank) -> fp64 top10 -> gather-max -------
__global__ __launch_bounds__(192) void k_out(const float* __restrict__ y,
                                             const float* __restrict__ ptsT,
                                             const float* __restrict__ outS,
                                             const unsigned short* __restrict__ outI,
                                             float* __restrict__ out) {
    __shared__ float  sc[NR * LC];
    __shared__ int    ix[NR * LC];
    __shared__ float  s2[96];
    __shared__ int    i2[96];
    __shared__ int    c24[24];
    __shared__ double d2s[24];
    __shared__ int    ci[24];
    __shared__ __align__(16) float qs[Dims];
    __shared__ int    nb[KNN];

    const int n = blockIdx.x;
    const int t = threadIdx.x;

    if (t < Dims) qs[t] = ptsT[(size_t)n * Dims + t];
    {
        const int r = t / LC, k = t - r * LC;   // t < 192 = NR*LC
        sc[t] = outS[((size_t)r * Npts + n) * LC + k];
        ix[t] = (int)outI[((size_t)r * Npts + n) * LC + k];
    }
    __syncthreads();

    // phase 1: rank within group of 48, keep top-24 of each (4 groups -> 96)
    {
        const int gb = (t / 48) * 48;
        const float v = sc[t]; const int vi = ix[t];
        int rk = 0;
        for (int c = 0; c < 48; ++c) {
            float oc = sc[gb + c]; int oi = ix[gb + c];
            rk += (oc < v || (oc == v && oi < vi)) ? 1 : 0;
        }
        if (rk < 24) { s2[(t / 48) * 24 + rk] = v; i2[(t / 48) * 24 + rk] = vi; }
    }
    __syncthreads();

    // phase 2: 96 -> coarse top-24
    if (t < 96) {
        const float v = s2[t]; const int vi = i2[t];
        int rk = 0;
        for (int c = 0; c < 96; ++c)
            rk += (s2[c] < v || (s2[c] == v && i2[c] < vi)) ? 1 : 0;
        if (rk < 24) c24[rk] = vi;
    }
    __syncthreads();

    // exact fp64 d2 for 24 candidates
    if (t < 24) {
        const int j = c24[t];
        double acc = 0.0;
#pragma unroll
        for (int d4 = 0; d4 < Dims / 4; ++d4) {
            const float4 pv = *(const float4*)&ptsT[(size_t)j * Dims + d4 * 4];
            const float4 qv = *(const float4*)&qs[d4 * 4];
            double e0 = (double)qv.x - (double)pv.x;
            double e1 = (double)qv.y - (double)pv.y;
            double e2 = (double)qv.z - (double)pv.z;
            double e3 = (double)qv.w - (double)pv.w;
            acc = fma(e0, e0, acc); acc = fma(e1, e1, acc);
            acc = fma(e2, e2, acc); acc = fma(e3, e3, acc);
        }
        d2s[t] = acc; ci[t] = j;
    }
    __syncthreads();

    // exact top-10 by (d2, idx)
    if (t < 24) {
        const double dv = d2s[t]; const int ji = ci[t];
        int rk = 0;
        for (int c = 0; c < 24; ++c)
            rk += (d2s[c] < dv || (d2s[c] == dv && ci[c] < ji)) ? 1 : 0;
        if (rk < KNN) nb[rk] = ji;
    }
    __syncthreads();

    if (t < Oout) {
        float m = -FLT_MAX;
#pragma unroll
        for (int k = 0; k < KNN; ++k)
            m = fmaxf(m, y[(size_t)nb[k] * Oout + t]);
        out[(size_t)n * Oout + t] = m;
    }
}

// ---------------- launcher ----------------
extern "C" void kernel_launch(void* const* d_in, const int* in_sizes, int n_in,
                              void* d_out, int out_size, void* d_ws, size_t ws_size,
                              hipStream_t stream) {
    const float* x = (const float*)d_in[0];   // (1, 64, 16384)
    const float* W = (const float*)d_in[1];   // (128, 64)
    const float* b = (const float*)d_in[2];   // (128,)
    float* out = (float*)d_out;

    float* ws   = (float*)d_ws;
    float* sq   = ws;                                        // 16384        (64 KB)
    float* ptsT = ws + Npts;                                 // N*D          (4 MB)
    float* y    = ptsT + Npts * Dims;                        // N*O          (8 MB)
    unsigned short* xh = (unsigned short*)(y + Npts * Oout); // N*D bf16     (2 MB)
    float* outS = (float*)(xh + Npts * Dims);                // NR*N*LC f32  (12 MB)
    unsigned short* outI = (unsigned short*)(outS + (size_t)NR * Npts * LC); // (6 MB)

    k_tr <<<Npts / 64, 256, 0, stream>>>(x, ptsT, xh, sq);
    k_y  <<<Npts / 8, 256, 0, stream>>>(ptsT, W, b, y);
    k_knn<<<256 * 4, 256, 0, stream>>>(xh, sq, outS, outI);
    k_out<<<Npts, 192, 0, stream>>>(y, ptsT, outS, outI, out);
}

// Round 10
// 331.890 us; speedup vs baseline: 1.3347x; 1.0811x over previous
//
#include <hip/hip_runtime.h>
#include <hip/hip_bf16.h>
#include <float.h>

#define Npts 16384
#define Dims 64
#define Oout 128
#define KNN  10
#define LC   12                      // per-query coarse list
#define NR   16                      // candidate ranges
#define RLEN (Npts / NR)             // 1024
#define NCG  (RLEN / 16)             // 64 cand-groups of 16
#define QCAP 21                      // queue slots (22 with pad)

typedef __attribute__((ext_vector_type(8))) short s16x8;
typedef __attribute__((ext_vector_type(4))) float f32x4;

__device__ __forceinline__ unsigned short f2bf(float f) {
    unsigned u = __float_as_uint(f);
    return (unsigned short)((u + 0x7FFFu + ((u >> 16) & 1u)) >> 16);
}
// bf16 * (-2): flip sign, exp+1 (exact; zero/denorm handled)
__device__ __forceinline__ short neg2(short hs) {
    unsigned short h = (unsigned short)hs;
    unsigned short m = (unsigned short)(h ^ 0x8000u);
    return (short)(((h & 0x7F80u) == 0) ? m : (unsigned short)(m + 0x0080u));
}

__device__ __forceinline__ void insertL(float (&bd)[LC], int (&bi)[LC], float s, int j) {
    if (s < bd[LC - 1]) {
#pragma unroll
        for (int k = LC - 1; k >= 1; --k) {
            bool up = bd[k - 1] > s;
            float nd = up ? bd[k - 1] : ((bd[k] > s) ? s : bd[k]);
            int   ni = up ? bi[k - 1] : ((bd[k] > s) ? j : bi[k]);
            bd[k] = nd; bi[k] = ni;
        }
        bool u0 = bd[0] > s;
        bi[0] = u0 ? j : bi[0];
        bd[0] = u0 ? s : bd[0];
    }
}

// ------- k_tr: transpose + bf16 hi split + sq -------
__global__ __launch_bounds__(256) void k_tr(const float* __restrict__ x,
                                            float* __restrict__ ptsT,
                                            unsigned short* __restrict__ xh,
                                            float* __restrict__ sq) {
    __shared__ float tile[64][65];
    const int b = blockIdx.x;
    for (int i = threadIdx.x; i < 64 * 64; i += 256) {
        int d = i >> 6, p = i & 63;
        tile[d][p] = x[d * Npts + b * 64 + p];
    }
    __syncthreads();
    for (int i = threadIdx.x; i < 64 * 64; i += 256) {
        int p = i >> 6, d = i & 63;
        float v = tile[d][p];
        ptsT[(b * 64 + p) * 64 + d] = v;
        xh[(b * 64 + p) * 64 + d] = (unsigned short)f2bf(v);
    }
    __syncthreads();
    if (threadIdx.x < 64) {
        int p = threadIdx.x;
        float a = 0.f;
#pragma unroll
        for (int d = 0; d < 64; ++d) { float v = tile[d][p]; a = fmaf(v, v, a); }
        sq[b * 64 + p] = a;
    }
}

// ------- k_y: y[n][o] = W[o]·pts[n] + b[o], LDS-tiled -------
__global__ __launch_bounds__(256) void k_y(const float* __restrict__ ptsT,
                                           const float* __restrict__ W,
                                           const float* __restrict__ bias,
                                           float* __restrict__ y) {
    __shared__ float wsh[128][65];
    __shared__ float xs[8][64];
    const int t = threadIdx.x;
    const int nb = blockIdx.x * 8;
    for (int i = t; i < 128 * 64; i += 256) {
        int o = i >> 6, d = i & 63;
        wsh[o][d] = W[i];
    }
    for (int i = t; i < 8 * 64; i += 256) {
        int n8 = i >> 6, d = i & 63;
        xs[n8][d] = ptsT[(nb + n8) * 64 + d];
    }
    __syncthreads();
    const int o = t & 127, nn = t >> 7;
    float a0 = bias[o], a1 = a0, a2 = a0, a3 = a0;
#pragma unroll
    for (int d = 0; d < 64; ++d) {
        float wv = wsh[o][d];
        a0 = fmaf(xs[nn * 4 + 0][d], wv, a0);
        a1 = fmaf(xs[nn * 4 + 1][d], wv, a1);
        a2 = fmaf(xs[nn * 4 + 2][d], wv, a2);
        a3 = fmaf(xs[nn * 4 + 3][d], wv, a3);
    }
    y[(nb + nn * 4 + 0) * 128 + o] = a0;
    y[(nb + nn * 4 + 1) * 128 + o] = a1;
    y[(nb + nn * 4 + 2) * 128 + o] = a2;
    y[(nb + nn * 4 + 3) * 128 + o] = a3;
}

// ------- k_knn: pipelined MFMA + LDS bounce; 4 blocks/CU resident -------
// grid: 256 qblocks x 4 rangeblocks; block 256 = 4 waves.
// Wave w handles range rb*4+w (1024 cands) for the block's 64 queries.
__global__ __launch_bounds__(256, 4) void k_knn(const unsigned short* __restrict__ xh,
                                                const float* __restrict__ sq,
                                                float* __restrict__ outS,
                                                unsigned short* __restrict__ outI) {
    __shared__ __align__(16) float tile[4][4][16][17];  // [wave][qg][col][16+1pad] 17.0 KB
    __shared__ unsigned qq[4][64][QCAP + 1];            // per-lane queues 22.0 KB

    const int t    = threadIdx.x;
    const int w    = __builtin_amdgcn_readfirstlane(t >> 6);   // uniform wave id
    const int l    = t & 63;
    const int c15  = l & 15;
    const int g    = l >> 4;
    const int qblk = blockIdx.x & 255;
    const int rb   = blockIdx.x >> 8;
    const int range = rb * 4 + w;
    const int rbase = range * RLEN;
    const float* sqp = sq + rbase;                       // uniform -> s_loads
    const unsigned short* xr = xh + (size_t)rbase * 64;

    // B-frags: queries scaled by -2 in bf16 (exact), so MFMA acc = -2*q.c
    s16x8 b0[4], b1[4];
#pragma unroll
    for (int qg = 0; qg < 4; ++qg) {
        const unsigned short* qp = xh + (size_t)(qblk * 64 + qg * 16 + c15) * 64 + g * 8;
        s16x8 h0 = *(const s16x8*)qp;
        s16x8 h1 = *(const s16x8*)(qp + 32);
#pragma unroll
        for (int e = 0; e < 8; ++e) { b0[qg][e] = neg2(h0[e]); b1[qg][e] = neg2(h1[e]); }
    }

    float bd[LC]; int bi[LC];
#pragma unroll
    for (int k = 0; k < LC; ++k) { bd[k] = FLT_MAX; bi[k] = -1; }
    float tau = FLT_MAX;
    int myq = 0;
    unsigned* myqq = &qq[w][l][0];

    // pipeline state: pending scores (prev group) + its sq slice + base idx
    f32x4 p0 = {FLT_MAX, FLT_MAX, FLT_MAX, FLT_MAX}, p1 = p0, p2 = p0, p3 = p0;
    float sp[16];
#pragma unroll
    for (int j = 0; j < 16; ++j) sp[j] = 0.f;
    int pb = 0;

    // A-frag prefetch (group 0)
    const unsigned short* ap0 = xr + (size_t)c15 * 64 + g * 8;
    s16x8 Ac0 = *(const s16x8*)ap0;
    s16x8 Ac1 = *(const s16x8*)(ap0 + 32);

#pragma unroll 2
    for (int ci = 0; ci < NCG; ++ci) {
        // prefetch next group's A-frags
        const int cn = (ci + 1 < NCG) ? ci + 1 : ci;
        const unsigned short* apn = xr + (size_t)(cn * 16 + c15) * 64 + g * 8;
        s16x8 An0 = *(const s16x8*)apn;
        s16x8 An1 = *(const s16x8*)(apn + 32);

        // sq slice for THIS group (consumed next iteration) - scalar loads
        float sn[16];
#pragma unroll
        for (int j = 0; j < 16; ++j) sn[j] = sqp[ci * 16 + j];

        // MFMA + LDS bounce (no fence: same-wave DS is in-order)
#pragma unroll
        for (int qg = 0; qg < 4; ++qg) {
            f32x4 acc = {0.f, 0.f, 0.f, 0.f};
            acc = __builtin_amdgcn_mfma_f32_16x16x32_bf16(Ac0, b0[qg], acc, 0, 0, 0);
            acc = __builtin_amdgcn_mfma_f32_16x16x32_bf16(Ac1, b1[qg], acc, 0, 0, 0);
            *(f32x4*)&tile[w][qg][c15][g * 4] = acc;
        }
        f32x4 n0 = *(const f32x4*)&tile[w][g][c15][0];
        f32x4 n1 = *(const f32x4*)&tile[w][g][c15][4];
        f32x4 n2 = *(const f32x4*)&tile[w][g][c15][8];
        f32x4 n3 = *(const f32x4*)&tile[w][g][c15][12];

        // filter PREVIOUS group's scores (regs long since waited)
        {
            const float sv[16] = {
                p0[0] + sp[0],  p0[1] + sp[1],  p0[2] + sp[2],  p0[3] + sp[3],
                p1[0] + sp[4],  p1[1] + sp[5],  p1[2] + sp[6],  p1[3] + sp[7],
                p2[0] + sp[8],  p2[1] + sp[9],  p2[2] + sp[10], p2[3] + sp[11],
                p3[0] + sp[12], p3[1] + sp[13], p3[2] + sp[14], p3[3] + sp[15]};
#pragma unroll
            for (int j = 0; j < 16; ++j) {
                unsigned e = (__float_as_uint(sv[j]) & ~1023u) | (unsigned)(pb + j);
                myqq[myq] = e;                      // unconditional write
                myq += (sv[j] < tau) ? 1 : 0;      // conditional bump
            }
        }

        // wave-uniform drain guard (invariant: myq<=5 at filter entry; <=21 after)
        if (__any(myq > 5)) {
            for (int i = 0; i < myq; ++i) {
                unsigned e = myqq[i];
                insertL(bd, bi, __uint_as_float(e & ~1023u), rbase + (int)(e & 1023u));
            }
            myq = 0;
            tau = bd[LC - 1];
        }

        // rotate pipeline state (unroll-2 lets the compiler rename these away)
        p0 = n0; p1 = n1; p2 = n2; p3 = n3;
#pragma unroll
        for (int j = 0; j < 16; ++j) sp[j] = sn[j];
        pb = ci * 16;
        Ac0 = An0; Ac1 = An1;
    }

    // final pending group
    {
        const float sv[16] = {
            p0[0] + sp[0],  p0[1] + sp[1],  p0[2] + sp[2],  p0[3] + sp[3],
            p1[0] + sp[4],  p1[1] + sp[5],  p1[2] + sp[6],  p1[3] + sp[7],
            p2[0] + sp[8],  p2[1] + sp[9],  p2[2] + sp[10], p2[3] + sp[11],
            p3[0] + sp[12], p3[1] + sp[13], p3[2] + sp[14], p3[3] + sp[15]};
#pragma unroll
        for (int j = 0; j < 16; ++j) {
            unsigned e = (__float_as_uint(sv[j]) & ~1023u) | (unsigned)(pb + j);
            myqq[myq] = e;
            myq += (sv[j] < tau) ? 1 : 0;
        }
    }
    if (__any(myq != 0)) {
        for (int i = 0; i < myq; ++i) {
            unsigned e = myqq[i];
            insertL(bd, bi, __uint_as_float(e & ~1023u), rbase + (int)(e & 1023u));
        }
    }

    // write this (range, query) sorted top-12
    const int q = qblk * 64 + l;
    float* os = outS + ((size_t)range * Npts + q) * LC;
    unsigned short* oi = outI + ((size_t)range * Npts + q) * LC;
#pragma unroll
    for (int k = 0; k < LC; ++k) {
        os[k] = bd[k];
        oi[k] = (unsigned short)bi[k];
    }
}

// ------- k_out: 192 coarse -> top24 (2-phase rank) -> fp64 top10 -> gather-max -------
__global__ __launch_bounds__(192) void k_out(const float* __restrict__ y,
                                             const float* __restrict__ ptsT,
                                             const float* __restrict__ outS,
                                             const unsigned short* __restrict__ outI,
                                             float* __restrict__ out) {
    __shared__ float  sc[NR * LC];
    __shared__ int    ix[NR * LC];
    __shared__ float  s2[96];
    __shared__ int    i2[96];
    __shared__ int    c24[24];
    __shared__ double d2s[24];
    __shared__ int    ci[24];
    __shared__ __align__(16) float qs[Dims];
    __shared__ int    nb[KNN];

    const int n = blockIdx.x;
    const int t = threadIdx.x;

    if (t < Dims) qs[t] = ptsT[(size_t)n * Dims + t];
    {
        const int r = t / LC, k = t - r * LC;   // t < 192 = NR*LC
        sc[t] = outS[((size_t)r * Npts + n) * LC + k];
        ix[t] = (int)outI[((size_t)r * Npts + n) * LC + k];
    }
    __syncthreads();

    // phase 1: rank within group of 48, keep top-24 of each (4 groups -> 96)
    {
        const int gb = (t / 48) * 48;
        const float v = sc[t]; const int vi = ix[t];
        int rk = 0;
        for (int c = 0; c < 48; ++c) {
            float oc = sc[gb + c]; int oi = ix[gb + c];
            rk += (oc < v || (oc == v && oi < vi)) ? 1 : 0;
        }
        if (rk < 24) { s2[(t / 48) * 24 + rk] = v; i2[(t / 48) * 24 + rk] = vi; }
    }
    __syncthreads();

    // phase 2: 96 -> coarse top-24
    if (t < 96) {
        const float v = s2[t]; const int vi = i2[t];
        int rk = 0;
        for (int c = 0; c < 96; ++c)
            rk += (s2[c] < v || (s2[c] == v && i2[c] < vi)) ? 1 : 0;
        if (rk < 24) c24[rk] = vi;
    }
    __syncthreads();

    // exact fp64 d2 for 24 candidates
    if (t < 24) {
        const int j = c24[t];
        double acc = 0.0;
#pragma unroll
        for (int d4 = 0; d4 < Dims / 4; ++d4) {
            const float4 pv = *(const float4*)&ptsT[(size_t)j * Dims + d4 * 4];
            const float4 qv = *(const float4*)&qs[d4 * 4];
            double e0 = (double)qv.x - (double)pv.x;
            double e1 = (double)qv.y - (double)pv.y;
            double e2 = (double)qv.z - (double)pv.z;
            double e3 = (double)qv.w - (double)pv.w;
            acc = fma(e0, e0, acc); acc = fma(e1, e1, acc);
            acc = fma(e2, e2, acc); acc = fma(e3, e3, acc);
        }
        d2s[t] = acc; ci[t] = j;
    }
    __syncthreads();

    // exact top-10 by (d2, idx)
    if (t < 24) {
        const double dv = d2s[t]; const int ji = ci[t];
        int rk = 0;
        for (int c = 0; c < 24; ++c)
            rk += (d2s[c] < dv || (d2s[c] == dv && ci[c] < ji)) ? 1 : 0;
        if (rk < KNN) nb[rk] = ji;
    }
    __syncthreads();

    if (t < Oout) {
        float m = -FLT_MAX;
#pragma unroll
        for (int k = 0; k < KNN; ++k)
            m = fmaxf(m, y[(size_t)nb[k] * Oout + t]);
        out[(size_t)n * Oout + t] = m;
    }
}

// ---------------- launcher ----------------
extern "C" void kernel_launch(void* const* d_in, const int* in_sizes, int n_in,
                              void* d_out, int out_size, void* d_ws, size_t ws_size,
                              hipStream_t stream) {
    const float* x = (const float*)d_in[0];   // (1, 64, 16384)
    const float* W = (const float*)d_in[1];   // (128, 64)
    const float* b = (const float*)d_in[2];   // (128,)
    float* out = (float*)d_out;

    float* ws   = (float*)d_ws;
    float* sq   = ws;                                        // 16384        (64 KB)
    float* ptsT = ws + Npts;                                 // N*D          (4 MB)
    float* y    = ptsT + Npts * Dims;                        // N*O          (8 MB)
    unsigned short* xh = (unsigned short*)(y + Npts * Oout); // N*D bf16     (2 MB)
    float* outS = (float*)(xh + Npts * Dims);                // NR*N*LC f32  (12 MB)
    unsigned short* outI = (unsigned short*)(outS + (size_t)NR * Npts * LC); // (6 MB)

    k_tr <<<Npts / 64, 256, 0, stream>>>(x, ptsT, xh, sq);
    k_y  <<<Npts / 8, 256, 0, stream>>>(ptsT, W, b, y);
    k_knn<<<256 * 4, 256, 0, stream>>>(xh, sq, outS, outI);
    k_out<<<Npts, 192, 0, stream>>>(y, ptsT, outS, outI, out);
}

// Round 11
// 305.401 us; speedup vs baseline: 1.4505x; 1.0867x over previous
//
#include <hip/hip_runtime.h>
#include <hip/hip_bf16.h>
#include <float.h>

#define Npts 16384
#define Dims 64
#define Oout 128
#define KNN  10
#define LC   12                      // per-query coarse list
#define NR   16                      // candidate ranges
#define RLEN (Npts / NR)             // 1024
#define NCG  (RLEN / 16)             // 64 cand-groups of 16
#define QW   23                      // queue words per lane (odd: coprime w/ 32 banks)

typedef __attribute__((ext_vector_type(8))) short s16x8;
typedef __attribute__((ext_vector_type(4))) float f32x4;

__device__ __forceinline__ unsigned short f2bf(float f) {
    unsigned u = __float_as_uint(f);
    return (unsigned short)((u + 0x7FFFu + ((u >> 16) & 1u)) >> 16);
}
__device__ __forceinline__ float bf2f(unsigned short b) {
    return __uint_as_float(((unsigned)b) << 16);
}
// bf16 * (-2): flip sign, exp+1 (exact; zero/denorm handled)
__device__ __forceinline__ short neg2(short hs) {
    unsigned short h = (unsigned short)hs;
    unsigned short m = (unsigned short)(h ^ 0x8000u);
    return (short)(((h & 0x7F80u) == 0) ? m : (unsigned short)(m + 0x0080u));
}

__device__ __forceinline__ void insertL(float (&bd)[LC], int (&bi)[LC], float s, int j) {
    if (s < bd[LC - 1]) {
#pragma unroll
        for (int k = LC - 1; k >= 1; --k) {
            bool up = bd[k - 1] > s;
            float nd = up ? bd[k - 1] : ((bd[k] > s) ? s : bd[k]);
            int   ni = up ? bi[k - 1] : ((bd[k] > s) ? j : bi[k]);
            bd[k] = nd; bi[k] = ni;
        }
        bool u0 = bd[0] > s;
        bi[0] = u0 ? j : bi[0];
        bd[0] = u0 ? s : bd[0];
    }
}

// ------- k_tr: transpose + bf16 hi split + sq-aux (bf16 hi/lo) -------
__global__ __launch_bounds__(256) void k_tr(const float* __restrict__ x,
                                            float* __restrict__ ptsT,
                                            unsigned short* __restrict__ xh,
                                            unsigned short* __restrict__ axh) {
    __shared__ float tile[64][65];
    const int b = blockIdx.x;
    for (int i = threadIdx.x; i < 64 * 64; i += 256) {
        int d = i >> 6, p = i & 63;
        tile[d][p] = x[d * Npts + b * 64 + p];
    }
    __syncthreads();
    for (int i = threadIdx.x; i < 64 * 64; i += 256) {
        int p = i >> 6, d = i & 63;
        float v = tile[d][p];
        ptsT[(b * 64 + p) * 64 + d] = v;
        xh[(b * 64 + p) * 64 + d] = (unsigned short)f2bf(v);
    }
    __syncthreads();
    if (threadIdx.x < 64) {
        int p = threadIdx.x;
        float a = 0.f;
#pragma unroll
        for (int d = 0; d < 64; ++d) { float v = tile[d][p]; a = fmaf(v, v, a); }
        unsigned short h = f2bf(a);
        unsigned short lo = f2bf(a - bf2f(h));
        s16x8 v8 = {(short)h, (short)lo, 0, 0, 0, 0, 0, 0};
        *(s16x8*)(axh + (size_t)(b * 64 + p) * 8) = v8;
    }
}

// ------- k_y: y[n][o] = W[o]·pts[n] + b[o], LDS-tiled -------
__global__ __launch_bounds__(256) void k_y(const float* __restrict__ ptsT,
                                           const float* __restrict__ W,
                                           const float* __restrict__ bias,
                                           float* __restrict__ y) {
    __shared__ float wsh[128][65];
    __shared__ float xs[8][64];
    const int t = threadIdx.x;
    const int nb = blockIdx.x * 8;
    for (int i = t; i < 128 * 64; i += 256) {
        int o = i >> 6, d = i & 63;
        wsh[o][d] = W[i];
    }
    for (int i = t; i < 8 * 64; i += 256) {
        int n8 = i >> 6, d = i & 63;
        xs[n8][d] = ptsT[(nb + n8) * 64 + d];
    }
    __syncthreads();
    const int o = t & 127, nn = t >> 7;
    float a0 = bias[o], a1 = a0, a2 = a0, a3 = a0;
#pragma unroll
    for (int d = 0; d < 64; ++d) {
        float wv = wsh[o][d];
        a0 = fmaf(xs[nn * 4 + 0][d], wv, a0);
        a1 = fmaf(xs[nn * 4 + 1][d], wv, a1);
        a2 = fmaf(xs[nn * 4 + 2][d], wv, a2);
        a3 = fmaf(xs[nn * 4 + 3][d], wv, a3);
    }
    y[(nb + nn * 4 + 0) * 128 + o] = a0;
    y[(nb + nn * 4 + 1) * 128 + o] = a1;
    y[(nb + nn * 4 + 2) * 128 + o] = a2;
    y[(nb + nn * 4 + 3) * 128 + o] = a3;
}

// ------- k_knn: score = MFMA(sq-fold); tau-filter; odd-stride queues -------
// grid: 256 qblocks x 4 rangeblocks; block 256 = 4 waves.
// Wave w handles range rb*4+w (1024 cands) for the block's 64 queries.
// S^T = mfma(A=cand, B=query): D[cand][query]; lane(c15,g) reg r = D[g*4+r][c15].
__global__ __launch_bounds__(256, 4) void k_knn(const unsigned short* __restrict__ xh,
                                                const unsigned short* __restrict__ axh,
                                                float* __restrict__ outS,
                                                unsigned short* __restrict__ outI) {
    __shared__ __align__(16) float tile[4][4][16][17];  // 17408 B, 2-way max
    __shared__ unsigned qq[4][64][QW];                  // 23552 B, stride-23
    // total LDS = 40960 B exactly -> 4 blocks/CU

    const int t    = threadIdx.x;
    const int w    = __builtin_amdgcn_readfirstlane(t >> 6);
    const int l    = t & 63;
    const int c15  = l & 15;
    const int g    = l >> 4;
    const int qblk = blockIdx.x & 255;
    const int rb   = blockIdx.x >> 8;
    const int range = rb * 4 + w;
    const int rbase = range * RLEN;
    const unsigned short* xr  = xh + (size_t)rbase * 64;
    const unsigned short* axr = axh + (size_t)rbase * 8;

    // B-frags: queries scaled by -2 in bf16 (exact) -> MFMA acc = -2*q.c
    s16x8 b0[4], b1[4];
#pragma unroll
    for (int qg = 0; qg < 4; ++qg) {
        const unsigned short* qp = xh + (size_t)(qblk * 64 + qg * 16 + c15) * 64 + g * 8;
        s16x8 h0 = *(const s16x8*)qp;
        s16x8 h1 = *(const s16x8*)(qp + 32);
#pragma unroll
        for (int e = 0; e < 8; ++e) { b0[qg][e] = neg2(h0[e]); b1[qg][e] = neg2(h1[e]); }
    }
    // sq-fold B-frag: B[k=0..1][*] = 1.0 (g==0 lanes only); garbage A annihilates vs 0
    s16x8 b2 = {0, 0, 0, 0, 0, 0, 0, 0};
    if (g == 0) { b2[0] = (short)0x3F80; b2[1] = (short)0x3F80; }

    float bd[LC]; int bi[LC];
#pragma unroll
    for (int k = 0; k < LC; ++k) { bd[k] = FLT_MAX; bi[k] = -1; }
    float tau = FLT_MAX;
    int myq = 0;
    unsigned* myqq = &qq[w][l][0];

    // A-frag prefetch (group 0): cand row + sq-aux
    const unsigned short* ap0 = xr + (size_t)c15 * 64 + g * 8;
    s16x8 Ac0 = *(const s16x8*)ap0;
    s16x8 Ac1 = *(const s16x8*)(ap0 + 32);
    s16x8 Ac2 = *(const s16x8*)(axr + (size_t)c15 * 8);

    for (int ci = 0; ci < NCG; ++ci) {
        // prefetch next group's A-frags (land under this group's filter)
        const int cn = (ci + 1 < NCG) ? ci + 1 : ci;
        const unsigned short* apn = xr + (size_t)(cn * 16 + c15) * 64 + g * 8;
        s16x8 An0 = *(const s16x8*)apn;
        s16x8 An1 = *(const s16x8*)(apn + 32);
        s16x8 An2 = *(const s16x8*)(axr + (size_t)(cn * 16 + c15) * 8);

        // score tile: acc = sq_j - 2*q.c  (sq folded via 3rd MFMA)
#pragma unroll
        for (int qg = 0; qg < 4; ++qg) {
            f32x4 acc = {0.f, 0.f, 0.f, 0.f};
            acc = __builtin_amdgcn_mfma_f32_16x16x32_bf16(Ac0, b0[qg], acc, 0, 0, 0);
            acc = __builtin_amdgcn_mfma_f32_16x16x32_bf16(Ac1, b1[qg], acc, 0, 0, 0);
            acc = __builtin_amdgcn_mfma_f32_16x16x32_bf16(Ac2, b2, acc, 0, 0, 0);
            *(f32x4*)&tile[w][qg][c15][g * 4] = acc;
        }
        // lane reads its own query's 16 scores (in-order same-wave DS)
        const f32x4 n0 = *(const f32x4*)&tile[w][g][c15][0];
        const f32x4 n1 = *(const f32x4*)&tile[w][g][c15][4];
        const f32x4 n2 = *(const f32x4*)&tile[w][g][c15][8];
        const f32x4 n3 = *(const f32x4*)&tile[w][g][c15][12];

        // filter: pack (AND-OR w/ SGPR const) + queue write + cmp + bump
        const unsigned pb = (unsigned)(ci * 16);
#pragma unroll
        for (int j = 0; j < 4; ++j) {
            unsigned e = (__float_as_uint(n0[j]) & ~1023u) | (pb + j);
            myqq[myq] = e;  myq += (n0[j] < tau) ? 1 : 0;
        }
#pragma unroll
        for (int j = 0; j < 4; ++j) {
            unsigned e = (__float_as_uint(n1[j]) & ~1023u) | (pb + 4 + j);
            myqq[myq] = e;  myq += (n1[j] < tau) ? 1 : 0;
        }
#pragma unroll
        for (int j = 0; j < 4; ++j) {
            unsigned e = (__float_as_uint(n2[j]) & ~1023u) | (pb + 8 + j);
            myqq[myq] = e;  myq += (n2[j] < tau) ? 1 : 0;
        }
#pragma unroll
        for (int j = 0; j < 4; ++j) {
            unsigned e = (__float_as_uint(n3[j]) & ~1023u) | (pb + 12 + j);
            myqq[myq] = e;  myq += (n3[j] < tau) ? 1 : 0;
        }

        // wave-uniform drain (invariant: myq<=6 at entry; max write idx 21 < 23)
        if (__any(myq > 6)) {
            for (int i = 0; i < myq; ++i) {
                unsigned e = myqq[i];
                insertL(bd, bi, __uint_as_float(e & ~1023u), rbase + (int)(e & 1023u));
            }
            myq = 0;
            tau = bd[LC - 1];
        }

        Ac0 = An0; Ac1 = An1; Ac2 = An2;
    }

    if (__any(myq != 0)) {
        for (int i = 0; i < myq; ++i) {
            unsigned e = myqq[i];
            insertL(bd, bi, __uint_as_float(e & ~1023u), rbase + (int)(e & 1023u));
        }
    }

    // write this (range, query) sorted top-12
    const int q = qblk * 64 + l;
    float* os = outS + ((size_t)range * Npts + q) * LC;
    unsigned short* oi = outI + ((size_t)range * Npts + q) * LC;
#pragma unroll
    for (int k = 0; k < LC; ++k) {
        os[k] = bd[k];
        oi[k] = (unsigned short)bi[k];
    }
}

// ------- k_out: 192 coarse -> top24 (2-phase rank) -> fp64 top10 -> gather-max -------
__global__ __launch_bounds__(192) void k_out(const float* __restrict__ y,
                                             const float* __restrict__ ptsT,
                                             const float* __restrict__ outS,
                                             const unsigned short* __restrict__ outI,
                                             float* __restrict__ out) {
    __shared__ float  sc[NR * LC];
    __shared__ int    ix[NR * LC];
    __shared__ float  s2[96];
    __shared__ int    i2[96];
    __shared__ int    c24[24];
    __shared__ double d2s[24];
    __shared__ int    ci[24];
    __shared__ __align__(16) float qs[Dims];
    __shared__ int    nb[KNN];

    const int n = blockIdx.x;
    const int t = threadIdx.x;

    if (t < Dims) qs[t] = ptsT[(size_t)n * Dims + t];
    {
        const int r = t / LC, k = t - r * LC;   // t < 192 = NR*LC
        sc[t] = outS[((size_t)r * Npts + n) * LC + k];
        ix[t] = (int)outI[((size_t)r * Npts + n) * LC + k];
    }
    __syncthreads();

    // phase 1: rank within group of 48, keep top-24 of each (4 groups -> 96)
    {
        const int gb = (t / 48) * 48;
        const float v = sc[t]; const int vi = ix[t];
        int rk = 0;
        for (int c = 0; c < 48; ++c) {
            float oc = sc[gb + c]; int oi = ix[gb + c];
            rk += (oc < v || (oc == v && oi < vi)) ? 1 : 0;
        }
        if (rk < 24) { s2[(t / 48) * 24 + rk] = v; i2[(t / 48) * 24 + rk] = vi; }
    }
    __syncthreads();

    // phase 2: 96 -> coarse top-24
    if (t < 96) {
        const float v = s2[t]; const int vi = i2[t];
        int rk = 0;
        for (int c = 0; c < 96; ++c)
            rk += (s2[c] < v || (s2[c] == v && i2[c] < vi)) ? 1 : 0;
        if (rk < 24) c24[rk] = vi;
    }
    __syncthreads();

    // exact fp64 d2 for 24 candidates
    if (t < 24) {
        const int j = c24[t];
        double acc = 0.0;
#pragma unroll
        for (int d4 = 0; d4 < Dims / 4; ++d4) {
            const float4 pv = *(const float4*)&ptsT[(size_t)j * Dims + d4 * 4];
            const float4 qv = *(const float4*)&qs[d4 * 4];
            double e0 = (double)qv.x - (double)pv.x;
            double e1 = (double)qv.y - (double)pv.y;
            double e2 = (double)qv.z - (double)pv.z;
            double e3 = (double)qv.w - (double)pv.w;
            acc = fma(e0, e0, acc); acc = fma(e1, e1, acc);
            acc = fma(e2, e2, acc); acc = fma(e3, e3, acc);
        }
        d2s[t] = acc; ci[t] = j;
    }
    __syncthreads();

    // exact top-10 by (d2, idx)
    if (t < 24) {
        const double dv = d2s[t]; const int ji = ci[t];
        int rk = 0;
        for (int c = 0; c < 24; ++c)
            rk += (d2s[c] < dv || (d2s[c] == dv && ci[c] < ji)) ? 1 : 0;
        if (rk < KNN) nb[rk] = ji;
    }
    __syncthreads();

    if (t < Oout) {
        float m = -FLT_MAX;
#pragma unroll
        for (int k = 0; k < KNN; ++k)
            m = fmaxf(m, y[(size_t)nb[k] * Oout + t]);
        out[(size_t)n * Oout + t] = m;
    }
}

// ---------------- launcher ----------------
extern "C" void kernel_launch(void* const* d_in, const int* in_sizes, int n_in,
                              void* d_out, int out_size, void* d_ws, size_t ws_size,
                              hipStream_t stream) {
    const float* x = (const float*)d_in[0];   // (1, 64, 16384)
    const float* W = (const float*)d_in[1];   // (128, 64)
    const float* b = (const float*)d_in[2];   // (128,)
    float* out = (float*)d_out;

    float* ws   = (float*)d_ws;
    float* ptsT = ws;                                        // N*D          (4 MB)
    float* y    = ptsT + (size_t)Npts * Dims;                // N*O          (8 MB)
    unsigned short* xh  = (unsigned short*)(y + (size_t)Npts * Oout); // N*D bf16 (2 MB)
    unsigned short* axh = xh + (size_t)Npts * Dims;          // N*8 bf16     (256 KB)
    float* outS = (float*)(axh + (size_t)Npts * 8);          // NR*N*LC f32  (12 MB)
    unsigned short* outI = (unsigned short*)(outS + (size_t)NR * Npts * LC); // (6 MB)

    k_tr <<<Npts / 64, 256, 0, stream>>>(x, ptsT, xh, axh);
    k_y  <<<Npts / 8, 256, 0, stream>>>(ptsT, W, b, y);
    k_knn<<<256 * 4, 256, 0, stream>>>(xh, axh, outS, outI);
    k_out<<<Npts, 192, 0, stream>>>(y, ptsT, outS, outI, out);
}